// Round 9
// baseline (105.361 us; speedup 1.0000x reference)
//
#include <hip/hip_runtime.h>

#define NQ 10
#define QD 6
#define DIN 512
#define DOUT 64

// All cross-lane via compiler intrinsics ONLY (R9/R10 lesson: inline-asm DPP
// is invisible to the hazard recognizer -> RA copies corrupt it).
template <int CTRL>
__device__ __forceinline__ float dppf(float v) {
    return __int_as_float(__builtin_amdgcn_mov_dpp(__float_as_int(v), CTRL, 0xF, 0xF, true));
}
// LDS-pipe xor-shuffle within 32-lane halves.
// masks: xor1=0x041F xor2=0x081F xor4=0x101F xor8=0x201F xor16=0x401F
template <int MASK>
__device__ __forceinline__ float swz(float v) {
    return __int_as_float(__builtin_amdgcn_ds_swizzle(__float_as_int(v), MASK));
}
__device__ __forceinline__ float bperm(float v, int xaddr) {
    return __int_as_float(__builtin_amdgcn_ds_bpermute(xaddr, __float_as_int(v)));
}

// ---- two-register half-swap primitives (VALU pipe) ----
// gfx950 semantics: pl32(a,b): a' = [a_lo | b_lo], b' = [a_hi | b_hi]
//                   pl16(a,b): per 32-half, a' = [a_q0|b_q0], b' = [a_q1|b_q1]
#if __has_builtin(__builtin_amdgcn_permlane32_swap)
__device__ __forceinline__ void pl32(float& a, float& b) {
    auto r = __builtin_amdgcn_permlane32_swap(__float_as_int(a), __float_as_int(b), false, false);
    a = __int_as_float(r[0]); b = __int_as_float(r[1]);
}
#else
__device__ __forceinline__ void pl32(float& a, float& b) {
    const int lane = threadIdx.x & 63;
    const int xaddr = ((threadIdx.x ^ 32) & 63) << 2;
    const float pa = bperm(a, xaddr);
    const float pb = bperm(b, xaddr);
    const bool hi = (lane & 32) != 0;
    const float na = hi ? pb : a;
    const float nb = hi ? b  : pa;
    a = na; b = nb;
}
#endif
#if __has_builtin(__builtin_amdgcn_permlane16_swap)
__device__ __forceinline__ void pl16(float& a, float& b) {
    auto r = __builtin_amdgcn_permlane16_swap(__float_as_int(a), __float_as_int(b), false, false);
    a = __int_as_float(r[0]); b = __int_as_float(r[1]);
}
#else
__device__ __forceinline__ void pl16(float& a, float& b) {
    const int lane = threadIdx.x & 63;
    const float pa = swz<0x401F>(a);
    const float pb = swz<0x401F>(b);
    const bool odd = (lane & 16) != 0;
    const float na = odd ? pb : a;
    const float nb = odd ? b  : pa;
    a = na; b = nb;
}
#endif

// sum over the 16-lane row, result broadcast within the row (DPP only)
__device__ __forceinline__ float rowred(float v) {
    v += dppf<0x128>(v); v += dppf<0x124>(v);
    v += dppf<0x122>(v); v += dppf<0x121>(v);
    return v;
}
// finish wave-64 reduction for 4 row-reduced values; totals broadcast to all
// lanes. Pure permlane/VALU. (Validated R2.)
__device__ __forceinline__ void fin4(float& a, float& b, float& c, float& d) {
    pl16(a, b); float z0 = a + b;
    pl16(c, d); float z1 = c + d;
    pl32(z0, z1); float t = z0 + z1;
    float u = t; pl32(t, u);
    b = t; pl16(t, b); a = t;
    d = u; pl16(u, d); c = u;
}
__device__ __forceinline__ void fin2(float& a, float& b) {
    pl16(a, b); float z = a + b;
    float z2 = z; pl32(z, z2); float t = z + z2;
    b = t; pl16(t, b); a = t;
}

__device__ __forceinline__ float tanh_fast(float x) {
    const float e = __expf(2.0f * x);
    return 1.0f - __fdividef(2.0f, e + 1.0f);
}

// One wave64 = TWO samples (R8/R9). Amp idx = (lane<<4) | r per sample; wires
// 0..5 = lane bits 5..0; w6..w9 = r bits 3..0. States As[16], Ds[16] are
// independent circuits sharing all gate coefficients and W1 loads — every
// dependency chain gets 2x independent work (latency-hiding ILP), total
// waves halve.
// CNOT fusion (validated R3..R11):
//   pre-CNOT+RY : (al,be) = cbit ? ( g, C) : (C, g),  g = tbit ? S : -S
//   RY+post-CNOT: (al,be) = cbit ? (-g, C) : (C, g)
// R13: tangent form — uniform C factors fold into F (w0,w1,w7,w8,w9 all
// layers; w3,w5 last layer). Pipe split per R7: w0/w1 permlane (VALU),
// w2..w5 ds_swizzle (DS), w6..w9 register pairs.
__global__ __launch_bounds__(256) void dqc_main(
    const float* __restrict__ x,
    const float* __restrict__ W1,
    const float* __restrict__ b1,
    const float* __restrict__ qw,
    const float* __restrict__ W2,
    const float* __restrict__ b2,
    float* __restrict__ out,
    const int B)
{
    // csl per layer (stride 24):
    // [C0,S0,C2,S2,C4,S4,C6,S6,C8,S8,pad2, C1,S1,C3,S3,C5,S5,C7,S7,C9,S9,pad2]
    // tsl per layer (stride 8): [T0,T7,T8,T9, T1,T3,T5, unused]
    __shared__ __align__(16) float csl[QD * 24];
    __shared__ __align__(16) float tsl[QD * 8];

    const int tid = threadIdx.x;
    if (tid < QD * NQ) {
        const int layer = tid / NQ, wire = tid - layer * NQ;
        const float h = qw[tid] * 0.5f;
        const float s = __sinf(h), c = __cosf(h);
        const int pos = layer * 24 + (wire & 1) * 12 + (wire >> 1) * 2;
        csl[pos] = c; csl[pos + 1] = s;
        int slot = -1;
        if (wire == 0) slot = 0; else if (wire == 7) slot = 1;
        else if (wire == 8) slot = 2; else if (wire == 9) slot = 3;
        else if (wire == 1) slot = 4; else if (wire == 3) slot = 5;
        else if (wire == 5) slot = 6;
        if (slot >= 0) tsl[layer * 8 + slot] = __fdividef(s, c);
    }

    const int lane = tid & 63;
    const int s0 = blockIdx.x * 8 + (tid >> 6) * 2;   // 2 samples per wave
    const int s1 = s0 + 1;
    const int bb0 = (s0 < B) ? s0 : (B - 1);
    const int bb1 = (s1 < B) ? s1 : (B - 1);

    // ---------- front-end: dot = x[s,:] @ W1 for BOTH samples ----------
    float xr0[8], xr1[8];
    {
        const float4* xp0 = (const float4*)(x + (size_t)bb0 * DIN + lane * 8);
        const float4* xp1 = (const float4*)(x + (size_t)bb1 * DIN + lane * 8);
        const float4 a0 = xp0[0], a1 = xp0[1];
        const float4 c0 = xp1[0], c1 = xp1[1];
        xr0[0]=a0.x; xr0[1]=a0.y; xr0[2]=a0.z; xr0[3]=a0.w;
        xr0[4]=a1.x; xr0[5]=a1.y; xr0[6]=a1.z; xr0[7]=a1.w;
        xr1[0]=c0.x; xr1[1]=c0.y; xr1[2]=c0.z; xr1[3]=c0.w;
        xr1[4]=c1.x; xr1[5]=c1.y; xr1[6]=c1.z; xr1[7]=c1.w;
    }
    float dA[NQ], dD[NQ];
    #pragma unroll
    for (int w = 0; w < NQ; ++w) { dA[w] = 0.f; dD[w] = 0.f; }
    {
        const float4* wp = (const float4*)(W1 + (size_t)lane * 8 * NQ);
        #pragma unroll
        for (int j = 0; j < 4; ++j) {
            const float4 f0 = wp[5*j], f1 = wp[5*j+1], f2 = wp[5*j+2],
                         f3 = wp[5*j+3], f4 = wp[5*j+4];
            const float xa0 = xr0[2*j], xb0 = xr0[2*j+1];
            const float xa1 = xr1[2*j], xb1 = xr1[2*j+1];
            dA[0]=fmaf(xa0,f0.x,dA[0]); dA[1]=fmaf(xa0,f0.y,dA[1]);
            dA[2]=fmaf(xa0,f0.z,dA[2]); dA[3]=fmaf(xa0,f0.w,dA[3]);
            dA[4]=fmaf(xa0,f1.x,dA[4]); dA[5]=fmaf(xa0,f1.y,dA[5]);
            dA[6]=fmaf(xa0,f1.z,dA[6]); dA[7]=fmaf(xa0,f1.w,dA[7]);
            dA[8]=fmaf(xa0,f2.x,dA[8]); dA[9]=fmaf(xa0,f2.y,dA[9]);
            dA[0]=fmaf(xb0,f2.z,dA[0]); dA[1]=fmaf(xb0,f2.w,dA[1]);
            dA[2]=fmaf(xb0,f3.x,dA[2]); dA[3]=fmaf(xb0,f3.y,dA[3]);
            dA[4]=fmaf(xb0,f3.z,dA[4]); dA[5]=fmaf(xb0,f3.w,dA[5]);
            dA[6]=fmaf(xb0,f4.x,dA[6]); dA[7]=fmaf(xb0,f4.y,dA[7]);
            dA[8]=fmaf(xb0,f4.z,dA[8]); dA[9]=fmaf(xb0,f4.w,dA[9]);
            dD[0]=fmaf(xa1,f0.x,dD[0]); dD[1]=fmaf(xa1,f0.y,dD[1]);
            dD[2]=fmaf(xa1,f0.z,dD[2]); dD[3]=fmaf(xa1,f0.w,dD[3]);
            dD[4]=fmaf(xa1,f1.x,dD[4]); dD[5]=fmaf(xa1,f1.y,dD[5]);
            dD[6]=fmaf(xa1,f1.z,dD[6]); dD[7]=fmaf(xa1,f1.w,dD[7]);
            dD[8]=fmaf(xa1,f2.x,dD[8]); dD[9]=fmaf(xa1,f2.y,dD[9]);
            dD[0]=fmaf(xb1,f2.z,dD[0]); dD[1]=fmaf(xb1,f2.w,dD[1]);
            dD[2]=fmaf(xb1,f3.x,dD[2]); dD[3]=fmaf(xb1,f3.y,dD[3]);
            dD[4]=fmaf(xb1,f3.z,dD[4]); dD[5]=fmaf(xb1,f3.w,dD[5]);
            dD[6]=fmaf(xb1,f4.x,dD[6]); dD[7]=fmaf(xb1,f4.y,dD[7]);
            dD[8]=fmaf(xb1,f4.z,dD[8]); dD[9]=fmaf(xb1,f4.w,dD[9]);
        }
    }
    #pragma unroll
    for (int w = 0; w < NQ; ++w) { dA[w] = rowred(dA[w]); dD[w] = rowred(dD[w]); }
    fin4(dA[0], dA[1], dA[2], dA[3]);
    fin4(dA[4], dA[5], dA[6], dA[7]);
    fin2(dA[8], dA[9]);
    fin4(dD[0], dD[1], dD[2], dD[3]);
    fin4(dD[4], dD[5], dD[6], dD[7]);
    fin2(dD[8], dD[9]);

    // u0 = cos(th2+pi/4), u1 = sin(th2+pi/4), th2 = tanh(dot+b1)*pi/4
    float uA0[NQ], uA1[NQ], uD0[NQ], uD1[NQ];
    #pragma unroll
    for (int w = 0; w < NQ; ++w) {
        const float bw = b1[w];
        const float phiA = fmaf(tanh_fast(dA[w] + bw),
                                0.78539816339744830962f, 0.78539816339744830962f);
        uA0[w] = __cosf(phiA);
        uA1[w] = __sinf(phiA);
        const float phiD = fmaf(tanh_fast(dD[w] + bw),
                                0.78539816339744830962f, 0.78539816339744830962f);
        uD0[w] = __cosf(phiD);
        uD1[w] = __sinf(phiD);
    }

    __syncthreads();  // csl/tsl ready (no early return above)

    // ---------- extracted factor F = prod of C over t-form gates ----------
    // (R2-validated accounting: C1 folded EVERY layer since w1 is t-form.)
    float F = 1.f;
    #pragma unroll
    for (int k = 0; k < QD; ++k) {
        const float* ce = csl + k * 24;
        F *= ce[0] * ce[18];    // C0 * C7
        F *= ce[8] * ce[20];    // C8 * C9
        F *= ce[12];            // C1 (w1 t-form in EVERY layer)
    }
    {   const float* c5 = csl + 5 * 24;
        F *= c5[14] * c5[16];   // C3 * C5 (last layer no-fuse t-form)
    }

    // ---------- initial product states, E_0 relabel + F folded ----------
    float As[16], Ds[16];
#define INIT_STATE(ST, U0, U1)                                               \
    {                                                                        \
        float lf = ((lane & 32) ? U1[0] : U0[0]);                            \
        lf *= ((((lane >> 4) ^ (lane >> 5)) & 1) ? U1[1] : U0[1]);           \
        lf *= ((lane & 8) ? U1[2] : U0[2]);                                  \
        lf *= ((((lane >> 2) ^ (lane >> 3)) & 1) ? U1[3] : U0[3]);           \
        lf *= ((lane & 2) ? U1[4] : U0[4]);                                  \
        lf *= (((lane ^ (lane >> 1)) & 1) ? U1[5] : U0[5]);                  \
        lf *= F;                                                             \
        float d1[2] = { lf * U0[6], lf * U1[6] };                            \
        float d2[4], d3[8];                                                  \
        _Pragma("unroll")                                                    \
        for (int i = 0; i < 4; ++i) {                                        \
            const int r3 = i >> 1, r2 = i & 1;                               \
            d2[i] = d1[r3] * (((r2 ^ r3) & 1) ? U1[7] : U0[7]);              \
        }                                                                    \
        _Pragma("unroll")                                                    \
        for (int i = 0; i < 8; ++i)                                          \
            d3[i] = d2[i >> 1] * ((i & 1) ? U1[8] : U0[8]);                  \
        _Pragma("unroll")                                                    \
        for (int i = 0; i < 8; ++i) {                                        \
            const int r1 = i & 1;                                            \
            ST[2*i]   = d3[i] * (r1 ? U1[9] : U0[9]);                        \
            ST[2*i+1] = d3[i] * (r1 ? U0[9] : U1[9]);                        \
        }                                                                    \
    }
    INIT_STATE(As, uA0, uA1)
    INIT_STATE(Ds, uD0, uD1)

    // ---------- 6 fused layers (both states, shared coefficients) ----------
    #pragma unroll 1
    for (int k = 0; k < QD; ++k) {
        const float* ce = csl + k * 24;
        const float4 ea = *(const float4*)(ce);
        const float4 eb = *(const float4*)(ce + 4);
        const float4 tv = *(const float4*)(tsl + k * 8);
        const float4 tw = *(const float4*)(tsl + k * 8 + 4);
        const float C2=ea.z,S2=ea.w, C4=eb.x,S4=eb.y, C6=eb.z,S6=eb.w;
        const float T0=tv.x, T7=tv.y, T8=tv.z, T9=tv.w;
        const float T1=tw.x;

        // ==== even phase ====
        {   // w0 (t-form): pl32 pair trick (VALU) — 16 independent pairs
            #pragma unroll
            for (int i = 0; i < 8; ++i) {
                float u = As[2*i], v = As[2*i+1];
                pl32(u, v);
                float n0 = fmaf(-T0, v, u);
                float n1 = fmaf( T0, u, v);
                pl32(n0, n1);
                As[2*i] = n0; As[2*i+1] = n1;
            }
            #pragma unroll
            for (int i = 0; i < 8; ++i) {
                float u = Ds[2*i], v = Ds[2*i+1];
                pl32(u, v);
                float n0 = fmaf(-T0, v, u);
                float n1 = fmaf( T0, u, v);
                pl32(n0, n1);
                Ds[2*i] = n0; Ds[2*i+1] = n1;
            }
        }
#define GATE_XOR2(MASK, AL, BE)                                              \
        {                                                                    \
            float pA[16], pD[16];                                            \
            _Pragma("unroll")                                                \
            for (int r = 0; r < 16; ++r) pA[r] = swz<MASK>(As[r]);           \
            _Pragma("unroll")                                                \
            for (int r = 0; r < 16; ++r) pD[r] = swz<MASK>(Ds[r]);           \
            _Pragma("unroll")                                                \
            for (int r = 0; r < 16; ++r) As[r] = fmaf(AL, As[r], BE * pA[r]);\
            _Pragma("unroll")                                                \
            for (int r = 0; r < 16; ++r) Ds[r] = fmaf(AL, Ds[r], BE * pD[r]);\
        }
        {   // w2 + pre C(1,2): xor8 (DS), ctrl lane b4
            const float g = (lane & 8) ? S2 : -S2;
            const bool cb = (lane & 16) != 0;
            const float al = cb ? g : C2, be = cb ? C2 : g;
            GATE_XOR2(0x201F, al, be)
        }
        {   // w4 + pre C(3,4): xor2 (DS), ctrl lane b2
            const float g = (lane & 2) ? S4 : -S4;
            const bool cb = (lane & 4) != 0;
            const float al = cb ? g : C4, be = cb ? C4 : g;
            GATE_XOR2(0x081F, al, be)
        }
        {   // w6 + pre C(5,6): reg pairs (r, r+8), ctrl lane b0 (runtime)
            const bool cb = (lane & 1) != 0;
            const float a_lo = cb ? -S6 : C6, b_lo = cb ? C6 : -S6;
            const float a_hi = cb ?  S6 : C6, b_hi = cb ? C6 :  S6;
            #pragma unroll
            for (int r = 0; r < 8; ++r) {
                const float lo = As[r], hi = As[r + 8];
                As[r]     = fmaf(a_lo, lo, b_lo * hi);
                As[r + 8] = fmaf(a_hi, hi, b_hi * lo);
            }
            #pragma unroll
            for (int r = 0; r < 8; ++r) {
                const float lo = Ds[r], hi = Ds[r + 8];
                Ds[r]     = fmaf(a_lo, lo, b_lo * hi);
                Ds[r + 8] = fmaf(a_hi, hi, b_hi * lo);
            }
        }
        {   // w8 + pre C(7,8) (t-form): reg pairs (r, r+2), ctrl r bit2
            #pragma unroll
            for (int r = 0; r < 16; ++r) {
                if (r & 2) continue;
                const float lo = As[r], hi = As[r + 2];
                if (r & 4) { As[r] = fmaf(-T8, lo, hi); As[r+2] = fmaf( T8, hi, lo); }
                else       { As[r] = fmaf(-T8, hi, lo); As[r+2] = fmaf( T8, lo, hi); }
            }
            #pragma unroll
            for (int r = 0; r < 16; ++r) {
                if (r & 2) continue;
                const float lo = Ds[r], hi = Ds[r + 2];
                if (r & 4) { Ds[r] = fmaf(-T8, lo, hi); Ds[r+2] = fmaf( T8, hi, lo); }
                else       { Ds[r] = fmaf(-T8, hi, lo); Ds[r+2] = fmaf( T8, lo, hi); }
            }
        }

        // ==== odd phase ====
        if (k != QD - 1) {
            const float4 oa = *(const float4*)(ce + 12);
            const float2 ob = *(const float2*)(ce + 16);
            const float C3=oa.z,S3=oa.w, C5=ob.x,S5=ob.y;

            {   // w1 + post C(0,1) (t-form): pl16 pair trick, ctrl lane b5
                const bool cb = (lane & 32) != 0;
                #pragma unroll
                for (int i = 0; i < 8; ++i) {
                    float u = As[2*i], v = As[2*i+1];
                    pl16(u, v);
                    const float q0 = fmaf(-T1, v, u);
                    const float q1 = fmaf( T1, u, v);
                    float n0 = cb ? q1 : q0;
                    float n1 = cb ? q0 : q1;
                    pl16(n0, n1);
                    As[2*i] = n0; As[2*i+1] = n1;
                }
                #pragma unroll
                for (int i = 0; i < 8; ++i) {
                    float u = Ds[2*i], v = Ds[2*i+1];
                    pl16(u, v);
                    const float q0 = fmaf(-T1, v, u);
                    const float q1 = fmaf( T1, u, v);
                    float n0 = cb ? q1 : q0;
                    float n1 = cb ? q0 : q1;
                    pl16(n0, n1);
                    Ds[2*i] = n0; Ds[2*i+1] = n1;
                }
            }
            {   // w3 + post C(2,3): xor4 (DS), ctrl lane b3
                const float g = (lane & 4) ? S3 : -S3;
                const bool cb = (lane & 8) != 0;
                const float al = cb ? -g : C3, be = cb ? C3 : g;
                GATE_XOR2(0x101F, al, be)
            }
            {   // w5 + post C(4,5): xor1 (DS), ctrl lane b1
                const float g = (lane & 1) ? S5 : -S5;
                const bool cb = (lane & 2) != 0;
                const float al = cb ? -g : C5, be = cb ? C5 : g;
                GATE_XOR2(0x041F, al, be)
            }
            {   // w7 + post C(6,7) (t-form, fuse): pairs (r, r+4), ctrl r bit3
                #pragma unroll
                for (int r = 0; r < 16; ++r) {
                    if (r & 4) continue;
                    const float lo = As[r], hi = As[r + 4];
                    if (r & 8) { As[r] = fmaf( T7, lo, hi); As[r+4] = fmaf(-T7, hi, lo); }
                    else       { As[r] = fmaf(-T7, hi, lo); As[r+4] = fmaf( T7, lo, hi); }
                }
                #pragma unroll
                for (int r = 0; r < 16; ++r) {
                    if (r & 4) continue;
                    const float lo = Ds[r], hi = Ds[r + 4];
                    if (r & 8) { Ds[r] = fmaf( T7, lo, hi); Ds[r+4] = fmaf(-T7, hi, lo); }
                    else       { Ds[r] = fmaf(-T7, hi, lo); Ds[r+4] = fmaf( T7, lo, hi); }
                }
            }
            {   // w9 + post C(8,9) (t-form, fuse): pairs (r, r+1), ctrl r bit1
                #pragma unroll
                for (int r = 0; r < 16; r += 2) {
                    const float xv = As[r], yv = As[r + 1];
                    if (r & 2) { As[r] = fmaf( T9, xv, yv); As[r+1] = fmaf(-T9, yv, xv); }
                    else       { As[r] = fmaf(-T9, yv, xv); As[r+1] = fmaf( T9, xv, yv); }
                }
                #pragma unroll
                for (int r = 0; r < 16; r += 2) {
                    const float xv = Ds[r], yv = Ds[r + 1];
                    if (r & 2) { Ds[r] = fmaf( T9, xv, yv); Ds[r+1] = fmaf(-T9, yv, xv); }
                    else       { Ds[r] = fmaf(-T9, yv, xv); Ds[r+1] = fmaf( T9, xv, yv); }
                }
            }
        } else {
            // last layer: no post-CNOT anywhere -> all plain RY, all t-form
            const float T3 = tw.y, T5 = tw.z;

            {   // w1: pl16 pair trick, no CNOT
                #pragma unroll
                for (int i = 0; i < 8; ++i) {
                    float u = As[2*i], v = As[2*i+1];
                    pl16(u, v);
                    float q0 = fmaf(-T1, v, u);
                    float q1 = fmaf( T1, u, v);
                    pl16(q0, q1);
                    As[2*i] = q0; As[2*i+1] = q1;
                }
                #pragma unroll
                for (int i = 0; i < 8; ++i) {
                    float u = Ds[2*i], v = Ds[2*i+1];
                    pl16(u, v);
                    float q0 = fmaf(-T1, v, u);
                    float q1 = fmaf( T1, u, v);
                    pl16(q0, q1);
                    Ds[2*i] = q0; Ds[2*i+1] = q1;
                }
            }
            {   // w3: xor4 (DS), t-form
                const float t3 = (lane & 4) ? T3 : -T3;
                GATE_XOR2(0x101F, 1.0f, t3)
            }
            {   // w5: xor1 (DS), t-form
                const float t5 = (lane & 1) ? T5 : -T5;
                GATE_XOR2(0x041F, 1.0f, t5)
            }
            {   // w7 (t-form, no fuse)
                #pragma unroll
                for (int r = 0; r < 16; ++r) {
                    if (r & 4) continue;
                    const float lo = As[r], hi = As[r + 4];
                    As[r]     = fmaf(-T7, hi, lo);
                    As[r + 4] = fmaf( T7, lo, hi);
                }
                #pragma unroll
                for (int r = 0; r < 16; ++r) {
                    if (r & 4) continue;
                    const float lo = Ds[r], hi = Ds[r + 4];
                    Ds[r]     = fmaf(-T7, hi, lo);
                    Ds[r + 4] = fmaf( T7, lo, hi);
                }
            }
            {   // w9 (t-form, no fuse)
                #pragma unroll
                for (int r = 0; r < 16; r += 2) {
                    const float xv = As[r], yv = As[r + 1];
                    As[r]     = fmaf(-T9, yv, xv);
                    As[r + 1] = fmaf( T9, xv, yv);
                }
                #pragma unroll
                for (int r = 0; r < 16; r += 2) {
                    const float xv = Ds[r], yv = Ds[r + 1];
                    Ds[r]     = fmaf(-T9, yv, xv);
                    Ds[r + 1] = fmaf( T9, xv, yv);
                }
            }
        }
    }

    // ---------- expvals <Z_w> for both samples ----------
#define EXPVALS(ST, EV)                                                      \
    {                                                                        \
        float tot = 0.f, q6 = 0.f, q7 = 0.f, q8 = 0.f, q9 = 0.f;             \
        _Pragma("unroll")                                                    \
        for (int r = 0; r < 16; ++r) {                                       \
            const float P = ST[r] * ST[r];                                   \
            tot += P;                                                        \
            if (r & 8) q6 += P;                                              \
            if (r & 4) q7 += P;                                              \
            if (r & 2) q8 += P;                                              \
            if (r & 1) q9 += P;                                              \
        }                                                                    \
        EV[0] = (lane & 32) ? -tot : tot;                                    \
        EV[1] = (lane & 16) ? -tot : tot;                                    \
        EV[2] = (lane & 8)  ? -tot : tot;                                    \
        EV[3] = (lane & 4)  ? -tot : tot;                                    \
        EV[4] = (lane & 2)  ? -tot : tot;                                    \
        EV[5] = (lane & 1)  ? -tot : tot;                                    \
        EV[6] = fmaf(-2.f, q6, tot);                                         \
        EV[7] = fmaf(-2.f, q7, tot);                                         \
        EV[8] = fmaf(-2.f, q8, tot);                                         \
        EV[9] = fmaf(-2.f, q9, tot);                                         \
    }
    float eA[NQ], eD[NQ];
    EXPVALS(As, eA)
    EXPVALS(Ds, eD)
    #pragma unroll
    for (int w = 0; w < NQ; ++w) { eA[w] = rowred(eA[w]); eD[w] = rowred(eD[w]); }
    fin4(eA[0], eA[1], eA[2], eA[3]);
    fin4(eA[4], eA[5], eA[6], eA[7]);
    fin2(eA[8], eA[9]);
    fin4(eD[0], eD[1], eD[2], eD[3]);
    fin4(eD[4], eD[5], eD[6], eD[7]);
    fin2(eD[8], eD[9]);

    // ---------- output GEMM: lane = output column ----------
    {
        float w2c[NQ];
        #pragma unroll
        for (int w = 0; w < NQ; ++w) w2c[w] = W2[w * DOUT + lane];
        if (s0 < B) {
            float o = b2[lane];
            #pragma unroll
            for (int w = 0; w < NQ; ++w) o = fmaf(eA[w], w2c[w], o);
            out[(size_t)s0 * DOUT + lane] = o;
        }
        if (s1 < B) {
            float o = b2[lane];
            #pragma unroll
            for (int w = 0; w < NQ; ++w) o = fmaf(eD[w], w2c[w], o);
            out[(size_t)s1 * DOUT + lane] = o;
        }
    }
}

extern "C" void kernel_launch(void* const* d_in, const int* in_sizes, int n_in,
                              void* d_out, int out_size, void* d_ws, size_t ws_size,
                              hipStream_t stream) {
    const float* x  = (const float*)d_in[0];
    const float* W1 = (const float*)d_in[1];
    const float* b1 = (const float*)d_in[2];
    const float* qw = (const float*)d_in[3];
    const float* W2 = (const float*)d_in[4];
    const float* b2 = (const float*)d_in[5];
    float* out = (float*)d_out;

    const int B = in_sizes[0] / DIN;
    const int blocks = (B + 7) / 8;   // 8 samples per 256-thread block (2/wave)
    dqc_main<<<blocks, 256, 0, stream>>>(x, W1, b1, qw, W2, b2, out, B);
}